// Round 1
// baseline (414.203 us; speedup 1.0000x reference)
//
#include <hip/hip_runtime.h>
#include <math.h>

#define DIM 64

// Kernel 1: per-node scores a_src[i] = x[i,:] . w_src ; a_dst[i] = x[i,:] . w_dst
// One wave (64 lanes) per node: coalesced row read, dual shuffle reduction.
__global__ void score_kernel(const float* __restrict__ x,
                             const float* __restrict__ w_src,
                             const float* __restrict__ w_dst,
                             float* __restrict__ a_src,
                             float* __restrict__ a_dst,
                             int N) {
    int gid  = blockIdx.x * blockDim.x + threadIdx.x;
    int node = gid >> 6;          // wave index = node
    int lane = threadIdx.x & 63;
    if (node >= N) return;
    float xv = x[(size_t)node * DIM + lane];
    float s1 = xv * w_src[lane];
    float s2 = xv * w_dst[lane];
    #pragma unroll
    for (int off = 32; off > 0; off >>= 1) {
        s1 += __shfl_down(s1, off, 64);
        s2 += __shfl_down(s2, off, 64);
    }
    if (lane == 0) {
        a_src[node] = s1;
        a_dst[node] = s2;
    }
}

// Kernel 2: per-edge attention + scatter. One wave per edge; lane d owns dim d.
// h[dst, d] += tanh(a_src[src] + a_dst[dst]) * ew[e] * x[src, d]
__global__ void edge_kernel(const float* __restrict__ x,
                            const float* __restrict__ ew,
                            const int* __restrict__ src_idx,
                            const int* __restrict__ dst_idx,
                            const float* __restrict__ a_src,
                            const float* __restrict__ a_dst,
                            float* __restrict__ h,
                            int E) {
    int gid  = blockIdx.x * blockDim.x + threadIdx.x;
    int e    = gid >> 6;          // wave index = edge
    int lane = threadIdx.x & 63;
    if (e >= E) return;
    int s = src_idx[e];           // wave-uniform loads (broadcast)
    int t = dst_idx[e];
    float a  = tanhf(a_src[s] + a_dst[t]) * ew[e];
    float xv = x[(size_t)s * DIM + lane];   // coalesced 256B gather per wave
    atomicAdd(&h[(size_t)t * DIM + lane], a * xv);
}

extern "C" void kernel_launch(void* const* d_in, const int* in_sizes, int n_in,
                              void* d_out, int out_size, void* d_ws, size_t ws_size,
                              hipStream_t stream) {
    const float* x     = (const float*)d_in[0];
    const float* w_src = (const float*)d_in[1];
    const float* w_dst = (const float*)d_in[2];
    const float* ew    = (const float*)d_in[3];
    const int*   src   = (const int*)d_in[4];
    const int*   dst   = (const int*)d_in[5];
    float* h = (float*)d_out;

    int N = in_sizes[0] / DIM;
    int E = in_sizes[3];

    // workspace: a_src[N], a_dst[N]
    float* a_src = (float*)d_ws;
    float* a_dst = a_src + N;

    // d_out is poisoned to 0xAA before every timed launch — zero it.
    hipMemsetAsync(d_out, 0, (size_t)out_size * sizeof(float), stream);

    // 256 threads = 4 waves per block; one wave per node / edge.
    int score_blocks = (N + 3) / 4;
    score_kernel<<<score_blocks, 256, 0, stream>>>(x, w_src, w_dst, a_src, a_dst, N);

    int edge_blocks = (E + 3) / 4;
    edge_kernel<<<edge_blocks, 256, 0, stream>>>(x, ew, src, dst, a_src, a_dst, h, E);
}

// Round 3
// 320.845 us; speedup vs baseline: 1.2910x; 1.2910x over previous
//
#include <hip/hip_runtime.h>
#include <math.h>

#define DIM 64

// ---------------- Kernel 1: per-node scores --------------------------------
__global__ void score_kernel(const float* __restrict__ x,
                             const float* __restrict__ w_src,
                             const float* __restrict__ w_dst,
                             float* __restrict__ a_src,
                             float* __restrict__ a_dst,
                             int N) {
    int gid  = blockIdx.x * blockDim.x + threadIdx.x;
    int node = gid >> 6;
    int lane = threadIdx.x & 63;
    if (node >= N) return;
    float xv = x[(size_t)node * DIM + lane];
    float s1 = xv * w_src[lane];
    float s2 = xv * w_dst[lane];
    #pragma unroll
    for (int off = 32; off > 0; off >>= 1) {
        s1 += __shfl_down(s1, off, 64);
        s2 += __shfl_down(s2, off, 64);
    }
    if (lane == 0) {
        a_src[node] = s1;
        a_dst[node] = s2;
    }
}

// ---------------- zero the histogram (no memset inside capture) ------------
__global__ void zero_int_kernel(int* __restrict__ p, int n) {
    int i = blockIdx.x * blockDim.x + threadIdx.x;
    if (i < n) p[i] = 0;
}

// ---------------- Kernel 2: histogram of dst -------------------------------
__global__ void hist_kernel(const int* __restrict__ dst, int* __restrict__ cnt,
                            int E, int N) {
    int e = blockIdx.x * blockDim.x + threadIdx.x;
    if (e >= E) return;
    unsigned t = (unsigned)dst[e];
    if (t < (unsigned)N) atomicAdd(&cnt[t], 1);
}

// ---------------- Kernels 3-5: exclusive scan of cnt -> offs ---------------
// Double-buffered Hillis-Steele, 256-wide blocks.
__global__ void scan_part(const int* __restrict__ cnt, int* __restrict__ offs,
                          int* __restrict__ bsum, int N) {
    __shared__ int buf[2][256];
    int tid = threadIdx.x;
    int i = blockIdx.x * 256 + tid;
    int v = (i < N) ? cnt[i] : 0;
    int sel = 0;
    buf[0][tid] = v;
    __syncthreads();
    for (int off = 1; off < 256; off <<= 1) {
        int nsel = sel ^ 1;
        buf[nsel][tid] = buf[sel][tid] + ((tid >= off) ? buf[sel][tid - off] : 0);
        __syncthreads();
        sel = nsel;
    }
    if (i < N) offs[i] = buf[sel][tid] - v;           // exclusive
    if (tid == 255) bsum[blockIdx.x] = buf[sel][255]; // block total
}

__global__ void scan_top(int* __restrict__ bsum, int* __restrict__ offs,
                         int NB, int N) {
    __shared__ int buf[2][512];
    int tid = threadIdx.x;
    int v = (tid < NB) ? bsum[tid] : 0;
    int sel = 0;
    buf[0][tid] = v;
    __syncthreads();
    for (int off = 1; off < 512; off <<= 1) {
        int nsel = sel ^ 1;
        buf[nsel][tid] = buf[sel][tid] + ((tid >= off) ? buf[sel][tid - off] : 0);
        __syncthreads();
        sel = nsel;
    }
    if (tid < NB) bsum[tid] = buf[sel][tid] - v;      // exclusive
    if (tid == 511) offs[N] = buf[sel][511];          // grand total
}

__global__ void scan_add(int* __restrict__ offs, int* __restrict__ cursor,
                         const int* __restrict__ bsum, int N) {
    int i = blockIdx.x * 256 + threadIdx.x;
    if (i < N) {
        int o = offs[i] + bsum[blockIdx.x];
        offs[i] = o;
        cursor[i] = o;
    }
}

// ---------------- Kernel 6: scatter edges into dst-sorted order (SoA) ------
__global__ void scatter_kernel(const float* __restrict__ ew,
                               const int* __restrict__ src_idx,
                               const int* __restrict__ dst_idx,
                               const float* __restrict__ a_src,
                               const float* __restrict__ a_dst,
                               int* __restrict__ cursor,
                               int* __restrict__ psrc,
                               float* __restrict__ pa,
                               int E, int N) {
    int e = blockIdx.x * blockDim.x + threadIdx.x;
    if (e >= E) return;
    unsigned s = (unsigned)src_idx[e];
    unsigned t = (unsigned)dst_idx[e];
    if (s >= (unsigned)N || t >= (unsigned)N) return;   // guard (no fault)
    float a = tanhf(a_src[s] + a_dst[t]) * ew[e];
    int p = atomicAdd(&cursor[t], 1);
    if ((unsigned)p < (unsigned)E) {                    // guard (no fault)
        psrc[p] = (int)s;
        pa[p]   = a;
    }
}

// ---------------- Kernel 7: gather per dst node, single write --------------
__global__ void gather_kernel(const float* __restrict__ x,
                              const int* __restrict__ psrc,
                              const float* __restrict__ pa,
                              const int* __restrict__ offs,
                              float* __restrict__ h,
                              int N, int E) {
    int gid  = blockIdx.x * blockDim.x + threadIdx.x;
    int t    = gid >> 6;
    int lane = threadIdx.x & 63;
    if (t >= N) return;
    int p   = offs[t];
    int end = offs[t + 1];
    if (p < 0) p = 0;
    if (end > E) end = E;                               // guard (no fault)
    float acc = 0.f;
    for (; p + 1 < end; p += 2) {
        int s0 = psrc[p];
        int s1 = psrc[p + 1];
        float a0 = pa[p];
        float a1 = pa[p + 1];
        if ((unsigned)s0 >= (unsigned)N) s0 = 0;
        if ((unsigned)s1 >= (unsigned)N) s1 = 0;
        float x0 = x[(size_t)s0 * DIM + lane];
        float x1 = x[(size_t)s1 * DIM + lane];
        acc = fmaf(a0, x0, acc);
        acc = fmaf(a1, x1, acc);
    }
    if (p < end) {
        int s0 = psrc[p];
        if ((unsigned)s0 >= (unsigned)N) s0 = 0;
        acc = fmaf(pa[p], x[(size_t)s0 * DIM + lane], acc);
    }
    h[(size_t)t * DIM + lane] = acc;
}

// ---------------- Fallback (round-1 atomic path) ---------------------------
__global__ void zero_out_kernel(float* __restrict__ p, int n) {
    int i = blockIdx.x * blockDim.x + threadIdx.x;
    if (i < n) p[i] = 0.f;
}

__global__ void edge_kernel_atomic(const float* __restrict__ x,
                                   const float* __restrict__ ew,
                                   const int* __restrict__ src_idx,
                                   const int* __restrict__ dst_idx,
                                   const float* __restrict__ a_src,
                                   const float* __restrict__ a_dst,
                                   float* __restrict__ h,
                                   int E) {
    int gid  = blockIdx.x * blockDim.x + threadIdx.x;
    int e    = gid >> 6;
    int lane = threadIdx.x & 63;
    if (e >= E) return;
    int s = src_idx[e];
    int t = dst_idx[e];
    float a  = tanhf(a_src[s] + a_dst[t]) * ew[e];
    float xv = x[(size_t)s * DIM + lane];
    atomicAdd(&h[(size_t)t * DIM + lane], a * xv);
}

extern "C" void kernel_launch(void* const* d_in, const int* in_sizes, int n_in,
                              void* d_out, int out_size, void* d_ws, size_t ws_size,
                              hipStream_t stream) {
    const float* x     = (const float*)d_in[0];
    const float* w_src = (const float*)d_in[1];
    const float* w_dst = (const float*)d_in[2];
    const float* ew    = (const float*)d_in[3];
    const int*   src   = (const int*)d_in[4];
    const int*   dst   = (const int*)d_in[5];
    float* h = (float*)d_out;

    int N = in_sizes[0] / DIM;
    int E = in_sizes[3];
    int NB = (N + 255) / 256;

    // workspace layout (4B units):
    // [a_src N][a_dst N][cnt N][offs N+1][cursor N][bsum NB][psrc E][pa E]
    float* a_src  = (float*)d_ws;
    float* a_dst  = a_src + N;
    int*   cnt    = (int*)(a_dst + N);
    int*   offs   = cnt + N;
    int*   cursor = offs + N + 1;
    int*   bsum   = cursor + N;
    int*   psrc   = bsum + NB;
    float* pa     = (float*)(psrc + E);
    size_t need   = ((size_t)(5 * N + 1 + NB) + 2 * (size_t)E) * 4;

    int score_blocks = (N + 255) / 256 * 4;   // ceil(N/4 waves-of-4) safe form
    score_blocks = (N + 3) / 4 + ((N & 3) ? 1 : 0);
    score_kernel<<<score_blocks, 256, 0, stream>>>(x, w_src, w_dst, a_src, a_dst, N);

    if (ws_size < need || NB > 512) {
        // fallback: round-1 atomic path (known-good)
        int ob = (out_size + 255) / 256;
        zero_out_kernel<<<ob, 256, 0, stream>>>(h, out_size);
        int edge_blocks = (E + 3) / 4;
        edge_kernel_atomic<<<edge_blocks, 256, 0, stream>>>(x, ew, src, dst,
                                                            a_src, a_dst, h, E);
        return;
    }

    zero_int_kernel<<<NB, 256, 0, stream>>>(cnt, N);
    int eb = (E + 255) / 256;
    hist_kernel<<<eb, 256, 0, stream>>>(dst, cnt, E, N);
    scan_part<<<NB, 256, 0, stream>>>(cnt, offs, bsum, N);
    scan_top<<<1, 512, 0, stream>>>(bsum, offs, NB, N);
    scan_add<<<NB, 256, 0, stream>>>(offs, cursor, bsum, N);
    scatter_kernel<<<eb, 256, 0, stream>>>(ew, src, dst, a_src, a_dst,
                                           cursor, psrc, pa, E, N);
    int gather_blocks = (N + 3) / 4 + ((N & 3) ? 1 : 0);
    gather_kernel<<<gather_blocks, 256, 0, stream>>>(x, psrc, pa, offs, h, N, E);
}